// Round 14
// baseline (191.974 us; speedup 1.0000x reference)
//
#include <hip/hip_runtime.h>

#define NB 64
#define NT 2048
#define NQD 512
#define NKD 512
#define NVD 512
#define NAD 256

typedef __attribute__((ext_vector_type(8))) short s16x8;
typedef __attribute__((ext_vector_type(4))) float fx4;
typedef __attribute__((ext_vector_type(4))) unsigned int u32x4;

__device__ __forceinline__ short f2bf(float x) {
  union { float f; unsigned u; } v; v.f = x;
  return (short)((v.u + 0x7fffu + ((v.u >> 16) & 1u)) >> 16);  // RNE
}

__device__ __forceinline__ unsigned cvt_pk_bf16(float lo, float hi) {
  unsigned r;
  asm("v_cvt_pk_bf16_f32 %0, %1, %2" : "=v"(r) : "v"(lo), "v"(hi));
  return r;
}

// tanh(x) = 1 - 2/(1+e^{2x});  exact saturation at +/-1, rel err ~1e-7
__device__ __forceinline__ float fast_tanh(float x) {
  float e = __expf(x + x);
  return 1.0f - 2.0f * __builtin_amdgcn_rcpf(e + 1.0f);
}

__device__ __forceinline__ void gload_lds16(const void* g, void* l) {
  __builtin_amdgcn_global_load_lds(
      (const __attribute__((address_space(1))) unsigned int*)g,
      (__attribute__((address_space(3))) unsigned int*)l, 16, 0, 0);
}

// ---- kernel 1: fused prep.
// blocks 0..63:  qpk[b][n] = query[b]·Wq[:,n] + bq[n] + bk[n]
// blocks 64..79: Bpk = Wk as bf16 packed in MFMA B-fragment lane order:
//   Bpk[(ks*1024 + wnt*64 + g*16 + h)*8 + j] = bf16(Wk[ks*32+g*8+j][wnt*16+h])
__global__ void prep_kernel(const float* __restrict__ query, const float* __restrict__ Wq,
                            const float* __restrict__ bq, const float* __restrict__ bk,
                            const float* __restrict__ Wk,
                            float* __restrict__ qpk, short* __restrict__ Bpk) {
  __shared__ float q[NQD];
  const int tid = threadIdx.x;
  if (blockIdx.x < NB) {
    const int b = blockIdx.x;
    for (int k = tid; k < NQD; k += 256) q[k] = query[b * NQD + k];
    __syncthreads();
    float acc = bq[tid] + bk[tid];
#pragma unroll 8
    for (int k = 0; k < NQD; ++k) acc += q[k] * Wq[k * NAD + tid];
    qpk[b * NAD + tid] = acc;
  } else {
    const int ks = blockIdx.x - NB;          // 0..15 (K-step)
#pragma unroll
    for (int rep = 0; rep < 4; ++rep) {
      const int o = rep * 256 + tid;         // chunk id within ks: 0..1023
      const int wnt = o >> 6;
      const int l = o & 63;
      const int g = l >> 4, h = l & 15;
      const int n = wnt * 16 + h;
      const int k0 = ks * 32 + g * 8;
      s16x8 v;
#pragma unroll
      for (int j = 0; j < 8; ++j) v[j] = f2bf(Wk[(size_t)(k0 + j) * NAD + n]);
      *(s16x8*)(Bpk + (size_t)(ks * 1024 + o) * 8) = v;
    }
  }
}

// ---- kernel 2: fused GEMM(key@Wk) + tanh + ·Wo reduce -> score[b*T+t]
// BM=32, FULL-K A-tile (32 rows x 2KB = one 64KB CONTIGUOUS region) staged
// once via global_load_lds DMA (16 x 1KB instr per wave, all in flight),
// single __syncthreads(), then a BARRIER-FREE K-loop: A frags from LDS
// (source-granule swizzle col^=row&15 keeps reads ~conflict-free), B frags
// from L2-resident Bpk (coalesced 1KB wave loads, compiler-pipelined).
// Contiguous HBM streams + DMA MLP + zero inner sync.
__global__ void __launch_bounds__(256, 2)
score_kernel(const float* __restrict__ key, const short* __restrict__ Bpk,
             const float* __restrict__ qpk, const float* __restrict__ Wo,
             float* __restrict__ score) {
  __shared__ float As[32 * 512];        // 64 KB; granule (row,c) holds src col c^(row&15)
  __shared__ float sred[4][32];
  const int tid = threadIdx.x;
  const int w = tid >> 6, l = tid & 63;
  const int g = l >> 4, h = l & 15;
  const int m0 = blockIdx.x * 32;       // 64 blocks/batch; tiles never span batches
  const int b = m0 >> 11;

  // ---- stage full A tile: 64 DMA instrs, each 1KB contiguous (lanes permuted)
  {
    const char* tile = (const char*)(key + (size_t)m0 * NKD);
#pragma unroll
    for (int i = 0; i < 16; ++i) {
      const int q = (w * 16 + i) * 64 + l;   // linear LDS granule (16B units)
      const int row = q >> 7;                // uniform within an instruction
      const int col = q & 127;
      const int sg = col ^ (row & 15);       // pre-swizzled source granule
      gload_lds16(tile + ((size_t)row * 128 + sg) * 16,
                  (char*)As + (size_t)(w * 16 + i) * 1024);
    }
  }
  __syncthreads();                           // the ONLY barrier before epilogue

  // B fragment base: nt-panels 512 shorts apart, K-steps 8192 shorts apart
  const short* bbase = Bpk + (size_t)(w * 256 + l) * 8;

  fx4 acc[2][4];
#pragma unroll
  for (int i = 0; i < 2; ++i)
#pragma unroll
    for (int j = 0; j < 4; ++j) acc[i][j] = fx4{0.f, 0.f, 0.f, 0.f};

  // ---- barrier-free K-loop (full unroll; compiler pipelines B loads freely)
#pragma unroll
  for (int ks = 0; ks < 16; ++ks) {
    s16x8 bfr[4];
#pragma unroll
    for (int nt = 0; nt < 4; ++nt)
      bfr[nt] = *(const s16x8*)(bbase + (size_t)ks * 8192 + nt * 512);
    s16x8 af[2];
#pragma unroll
    for (int mt = 0; mt < 2; ++mt) {
      const int R = mt * 16 + h;             // R & 15 == h
      const int kc = ks * 8 + g * 2;         // 16B-granule index within row
      const float* base = As + (size_t)R * 128 * 4;
      fx4 lo = *(const fx4*)(base + (size_t)(kc ^ h) * 4);        // k: kc*4..+3
      fx4 hi = *(const fx4*)(base + (size_t)((kc + 1) ^ h) * 4);  // k: +4..+7
      u32x4 uu;
      uu[0] = cvt_pk_bf16(lo[0], lo[1]);
      uu[1] = cvt_pk_bf16(lo[2], lo[3]);
      uu[2] = cvt_pk_bf16(hi[0], hi[1]);
      uu[3] = cvt_pk_bf16(hi[2], hi[3]);
      af[mt] = *(s16x8*)&uu;
    }
#pragma unroll
    for (int mt = 0; mt < 2; ++mt)
#pragma unroll
      for (int nt = 0; nt < 4; ++nt)
        acc[mt][nt] = __builtin_amdgcn_mfma_f32_16x16x32_bf16(af[mt], bfr[nt], acc[mt][nt], 0, 0, 0);
  }

  // epilogue: score row m = m0 + mt*16 + 4g + reg  (C layout col=h, row=4g+reg)
  float qv[4], wv[4];
#pragma unroll
  for (int nt = 0; nt < 4; ++nt) {
    const int n = w * 64 + nt * 16 + h;
    qv[nt] = qpk[b * NAD + n];
    wv[nt] = Wo[n];
  }
#pragma unroll
  for (int mt = 0; mt < 2; ++mt) {
#pragma unroll
    for (int rr = 0; rr < 4; ++rr) {
      float s = fast_tanh(acc[mt][0][rr] + qv[0]) * wv[0]
              + fast_tanh(acc[mt][1][rr] + qv[1]) * wv[1]
              + fast_tanh(acc[mt][2][rr] + qv[2]) * wv[2]
              + fast_tanh(acc[mt][3][rr] + qv[3]) * wv[3];
#pragma unroll
      for (int off = 1; off < 16; off <<= 1) s += __shfl_xor(s, off, 64);
      if (h == 0) sred[w][mt * 16 + g * 4 + rr] = s;
    }
  }
  __syncthreads();
  if (tid < 32)
    score[m0 + tid] = sred[0][tid] + sred[1][tid] + sred[2][tid] + sred[3][tid];
}

// ---- kernel 3: softmax over T per batch (bo dropped: softmax shift-invariant)
__global__ void softmax_kernel(const float* __restrict__ score, float* __restrict__ attn) {
  __shared__ float redm[4];
  __shared__ float reds[4];
  const int b = blockIdx.x, tid = threadIdx.x;
  const float* s = score + (size_t)b * NT;
  float v[8];
  float m = -3.0e38f;
#pragma unroll
  for (int j = 0; j < 8; ++j) { v[j] = s[tid + j * 256]; m = fmaxf(m, v[j]); }
#pragma unroll
  for (int off = 1; off < 64; off <<= 1) m = fmaxf(m, __shfl_xor(m, off, 64));
  if ((tid & 63) == 0) redm[tid >> 6] = m;
  __syncthreads();
  m = fmaxf(fmaxf(redm[0], redm[1]), fmaxf(redm[2], redm[3]));
  float sum = 0.f;
#pragma unroll
  for (int j = 0; j < 8; ++j) { v[j] = __expf(v[j] - m); sum += v[j]; }
#pragma unroll
  for (int off = 1; off < 64; off <<= 1) sum += __shfl_xor(sum, off, 64);
  if ((tid & 63) == 0) reds[tid >> 6] = sum;
  __syncthreads();
  sum = reds[0] + reds[1] + reds[2] + reds[3];
  const float inv = 1.0f / sum;
#pragma unroll
  for (int j = 0; j < 8; ++j) attn[(size_t)b * NT + tid + j * 256] = v[j] * inv;
}

// ---- kernel 4: partial context over 64-row t-chunks (float4 loads)
__global__ void ctx_partial_kernel(const float* __restrict__ attn, const float* __restrict__ value,
                                   float* __restrict__ partial) {
  __shared__ float a[64];
  __shared__ fx4 red[128];
  const int blk = blockIdx.x;       // b*32 + tc
  const int b = blk >> 5, tc = blk & 31;
  const int tid = threadIdx.x;
  if (tid < 64) a[tid] = attn[(size_t)b * NT + tc * 64 + tid];
  __syncthreads();
  const int half = tid >> 7;        // 0: even rows, 1: odd rows
  const int vi = (tid & 127) * 4;   // 128 threads cover VD=512
  const float* vp = value + ((size_t)b * NT + tc * 64 + half) * NVD + vi;
  fx4 s = fx4{0.f, 0.f, 0.f, 0.f};
#pragma unroll 8
  for (int t = 0; t < 64; t += 2) {
    fx4 x = *(const fx4*)(vp + (size_t)t * NVD);
    const float wt = a[t + half];
    s += x * wt;
  }
  if (half) red[tid & 127] = s;
  __syncthreads();
  if (!half) {
    s += red[tid];
    *(fx4*)(partial + (size_t)blk * NVD + vi) = s;
  }
}

// ---- kernel 5: reduce partials -> context
__global__ void ctx_reduce_kernel(const float* __restrict__ partial, float* __restrict__ ctx) {
  const int i = blockIdx.x * 256 + threadIdx.x;  // < NB*NVD
  const int b = i >> 9, v = i & (NVD - 1);
  float s = 0.f;
#pragma unroll
  for (int tc = 0; tc < 32; ++tc) s += partial[(size_t)(b * 32 + tc) * NVD + v];
  ctx[i] = s;
}

extern "C" void kernel_launch(void* const* d_in, const int* in_sizes, int n_in,
                              void* d_out, int out_size, void* d_ws, size_t ws_size,
                              hipStream_t stream) {
  const float* query = (const float*)d_in[0];
  const float* key   = (const float*)d_in[1];
  const float* value = (const float*)d_in[2];
  const float* Wq    = (const float*)d_in[3];
  const float* bq    = (const float*)d_in[4];
  const float* Wk    = (const float*)d_in[5];
  const float* bk    = (const float*)d_in[6];
  const float* Wo    = (const float*)d_in[7];
  // d_in[8] = bo: unused — softmax over T is invariant to a uniform shift.

  float* out  = (float*)d_out;
  float* ctx  = out;                // [B][VD]
  float* attn = out + NB * NVD;     // [B][T]

  char* ws = (char*)d_ws;
  float* qpk     = (float*)(ws);                                   // 64 KB
  short* Bpk     = (short*)(ws + 64 * 1024);                       // 256 KB
  float* score   = (float*)(ws + (64 + 256) * 1024);               // 512 KB
  float* partial = (float*)(ws + (64 + 256 + 512) * 1024);         // 4 MB

  prep_kernel<<<NB + 16, 256, 0, stream>>>(query, Wq, bq, bk, Wk, qpk, Bpk);
  score_kernel<<<(NB * NT) / 32, 256, 0, stream>>>(key, Bpk, qpk, Wo, score);
  softmax_kernel<<<NB, 256, 0, stream>>>(score, attn);
  ctx_partial_kernel<<<NB * 32, 256, 0, stream>>>(attn, value, partial);
  ctx_reduce_kernel<<<(NB * NVD) / 256, 256, 0, stream>>>(partial, ctx);
}

// Round 15
// 150.466 us; speedup vs baseline: 1.2759x; 1.2759x over previous
//
#include <hip/hip_runtime.h>

#define NB 64
#define NT 2048
#define NQD 512
#define NKD 512
#define NVD 512
#define NAD 256

typedef __attribute__((ext_vector_type(8))) short s16x8;
typedef __attribute__((ext_vector_type(4))) float fx4;
typedef __attribute__((ext_vector_type(4))) unsigned int u32x4;

__device__ __forceinline__ short f2bf(float x) {
  union { float f; unsigned u; } v; v.f = x;
  return (short)((v.u + 0x7fffu + ((v.u >> 16) & 1u)) >> 16);  // RNE
}

__device__ __forceinline__ unsigned cvt_pk_bf16(float lo, float hi) {
  unsigned r;
  asm("v_cvt_pk_bf16_f32 %0, %1, %2" : "=v"(r) : "v"(lo), "v"(hi));
  return r;
}

// tanh(x) = 1 - 2/(1+e^{2x});  exact saturation at +/-1, rel err ~1e-7
__device__ __forceinline__ float fast_tanh(float x) {
  float e = __expf(x + x);
  return 1.0f - 2.0f * __builtin_amdgcn_rcpf(e + 1.0f);
}

__device__ __forceinline__ void gload_lds16(const void* g, void* l) {
  __builtin_amdgcn_global_load_lds(
      (const __attribute__((address_space(1))) unsigned int*)g,
      (__attribute__((address_space(3))) unsigned int*)l, 16, 0, 0);
}

// ---- kernel 1: fused prep.
// blocks 0..63:  qpk[b][n] = query[b]·Wq[:,n] + bq[n] + bk[n]
// blocks 64..79: Bpk = Wk as bf16 packed in MFMA B-fragment lane order:
//   Bpk[(ks*1024 + wnt*64 + g*16 + h)*8 + j] = bf16(Wk[ks*32+g*8+j][wnt*16+h])
__global__ void prep_kernel(const float* __restrict__ query, const float* __restrict__ Wq,
                            const float* __restrict__ bq, const float* __restrict__ bk,
                            const float* __restrict__ Wk,
                            float* __restrict__ qpk, short* __restrict__ Bpk) {
  __shared__ float q[NQD];
  const int tid = threadIdx.x;
  if (blockIdx.x < NB) {
    const int b = blockIdx.x;
    for (int k = tid; k < NQD; k += 256) q[k] = query[b * NQD + k];
    __syncthreads();
    float acc = bq[tid] + bk[tid];
#pragma unroll 8
    for (int k = 0; k < NQD; ++k) acc += q[k] * Wq[k * NAD + tid];
    qpk[b * NAD + tid] = acc;
  } else {
    const int ks = blockIdx.x - NB;          // 0..15 (K-step)
#pragma unroll
    for (int rep = 0; rep < 4; ++rep) {
      const int o = rep * 256 + tid;         // chunk id within ks: 0..1023
      const int wnt = o >> 6;
      const int l = o & 63;
      const int g = l >> 4, h = l & 15;
      const int n = wnt * 16 + h;
      const int k0 = ks * 32 + g * 8;
      s16x8 v;
#pragma unroll
      for (int j = 0; j < 8; ++j) v[j] = f2bf(Wk[(size_t)(k0 + j) * NAD + n]);
      *(s16x8*)(Bpk + (size_t)(ks * 1024 + o) * 8) = v;
    }
  }
}

// ---- kernel 2: fused GEMM(key@Wk) + tanh + ·Wo reduce -> score[b*T+t]
// (R13 structure — best measured.) BM=128, 512 threads (2x4 wave grid),
// BK=32 chunks. Both operands via global_load_lds DMA: sound counted-vmcnt
// ledger (exactly 4 DMA/wave/chunk, zero compiler-scheduled global loads in
// the loop), chunk ck+1 stays in flight across the barrier.
__global__ void __launch_bounds__(512, 4)
score_kernel(const float* __restrict__ key, const short* __restrict__ Bpk,
             const float* __restrict__ qpk, const float* __restrict__ Wo,
             float* __restrict__ score) {
  __shared__ float As[2][128 * 32];     // 2 x 16 KB f32 (granule-swizzled content)
  __shared__ short Bs[2][256 * 32];     // 2 x 16 KB bf16 (fragment order)
  __shared__ float sred[4][128];
  const int tid = threadIdx.x;
  const int W = tid >> 6, l = tid & 63;
  const int wr = W >> 2, wc = W & 3;    // wave grid: 2 row-groups x 4 col-groups
  const int g = l >> 4, h = l & 15;
  const int m0 = blockIdx.x * 128;      // 16 blocks/batch; tiles never span batches
  const int b = m0 >> 11;

  // A staging: 1024 granules/chunk (128 rows x 8 granules of 4 f32).
  // Source col swizzled (c ^= row&7), LDS linear -> swizzled conflict-free reads.
  const float* srcA[2];
  int loffA[2];
#pragma unroll
  for (int i = 0; i < 2; ++i) {
    const int p = W * 128 + i * 64 + l;
    const int row = p >> 3, c = p & 7;
    srcA[i] = key + (size_t)(m0 + row) * NKD + ((c ^ (row & 7)) << 2);
    loffA[i] = (W * 128 + i * 64) * 16;   // wave-uniform
  }
  // B staging: 1024 granules/chunk, Bpk chunk is 16KB contiguous, linear copy
  const short* srcB[2];
  int loffB[2];
#pragma unroll
  for (int i = 0; i < 2; ++i) {
    const int o = W * 128 + i * 64 + l;
    srcB[i] = Bpk + (size_t)o * 8;
    loffB[i] = (W * 128 + i * 64) * 16;   // wave-uniform
  }

  auto stage = [&](int bb, int ck) {
#pragma unroll
    for (int i = 0; i < 2; ++i)
      gload_lds16(srcA[i] + ck * 32, (char*)&As[bb][0] + loffA[i]);
#pragma unroll
    for (int i = 0; i < 2; ++i)
      gload_lds16(srcB[i] + (size_t)ck * 8192, (char*)&Bs[bb][0] + loffB[i]);
  };

  // prologue: chunks 0 and 1 in flight (8 DMA/wave)
  stage(0, 0);
  stage(1, 1);

  fx4 acc[4][4];
#pragma unroll
  for (int i = 0; i < 4; ++i)
#pragma unroll
    for (int j = 0; j < 4; ++j) acc[i][j] = fx4{0.f, 0.f, 0.f, 0.f};

  for (int ck = 0; ck < 16; ++ck) {
    const int buf = ck & 1;
    // complete chunk ck (oldest 4/wave); chunk ck+1's 4 stay in flight
    if (ck < 15) asm volatile("s_waitcnt vmcnt(4)" ::: "memory");
    else         asm volatile("s_waitcnt vmcnt(0)" ::: "memory");
    __builtin_amdgcn_sched_barrier(0);
    __builtin_amdgcn_s_barrier();       // all waves' chunk-ck LDS writes visible

    s16x8 bfr[4];
#pragma unroll
    for (int nt = 0; nt < 4; ++nt)
      bfr[nt] = *(const s16x8*)((const char*)&Bs[buf][0] + ((wc * 4 + nt) * 64 + l) * 16);
#pragma unroll
    for (int mt = 0; mt < 4; ++mt) {
      const int R = wr * 64 + mt * 16 + h;
      const char* base = (const char*)&As[buf][0] + R * 128;
      fx4 lo = *(const fx4*)(base + (((g * 2    ) ^ (R & 7)) << 4));
      fx4 hi = *(const fx4*)(base + (((g * 2 + 1) ^ (R & 7)) << 4));
      u32x4 uu;
      uu[0] = cvt_pk_bf16(lo[0], lo[1]);
      uu[1] = cvt_pk_bf16(lo[2], lo[3]);
      uu[2] = cvt_pk_bf16(hi[0], hi[1]);
      uu[3] = cvt_pk_bf16(hi[2], hi[3]);
      const s16x8 af = *(s16x8*)&uu;
#pragma unroll
      for (int nt = 0; nt < 4; ++nt)
        acc[mt][nt] = __builtin_amdgcn_mfma_f32_16x16x32_bf16(af, bfr[nt], acc[mt][nt], 0, 0, 0);
    }

    __builtin_amdgcn_s_barrier();       // all waves done reading buf
    if (ck < 14) stage(buf, ck + 2);    // refill freed buffer, stay 2 ahead
  }

  // epilogue: row = m0 + wr*64 + mt*16 + 4g + reg; col n = wc*64 + nt*16 + h
  float qv[4], wv[4];
#pragma unroll
  for (int nt = 0; nt < 4; ++nt) {
    const int n = wc * 64 + nt * 16 + h;
    qv[nt] = qpk[b * NAD + n];
    wv[nt] = Wo[n];
  }
#pragma unroll
  for (int mt = 0; mt < 4; ++mt) {
#pragma unroll
    for (int rr = 0; rr < 4; ++rr) {
      float s = fast_tanh(acc[mt][0][rr] + qv[0]) * wv[0]
              + fast_tanh(acc[mt][1][rr] + qv[1]) * wv[1]
              + fast_tanh(acc[mt][2][rr] + qv[2]) * wv[2]
              + fast_tanh(acc[mt][3][rr] + qv[3]) * wv[3];
#pragma unroll
      for (int off = 1; off < 16; off <<= 1) s += __shfl_xor(s, off, 64);
      if (h == 0) sred[wc][wr * 64 + mt * 16 + g * 4 + rr] = s;
    }
  }
  __syncthreads();
  if (tid < 128)
    score[m0 + tid] = sred[0][tid] + sred[1][tid] + sred[2][tid] + sred[3][tid];
}

// ---- kernel 3: fused softmax + partial context per (b, 64-row t-chunk).
// Every block recomputes the batch softmax stats (m, Z) redundantly from the
// L2-resident score row — identical code+order per block => identical values
// (deterministic). Block (b,tc) writes attn[b, tc*64..+63] and its partial.
__global__ void ctx_sm_kernel(const float* __restrict__ score, const float* __restrict__ value,
                              float* __restrict__ attn, float* __restrict__ partial) {
  __shared__ float pa[NT];          // 8 KB: normalized p for the whole batch row
  __shared__ float redm[4];
  __shared__ float reds[4];
  __shared__ fx4 red[128];
  const int blk = blockIdx.x;       // b*32 + tc
  const int b = blk >> 5, tc = blk & 31;
  const int tid = threadIdx.x;

  // --- softmax over T (identical to the old softmax_kernel's reduction order)
  const float* s = score + (size_t)b * NT;
  float v[8];
  float m = -3.0e38f;
#pragma unroll
  for (int j = 0; j < 8; ++j) { v[j] = s[tid + j * 256]; m = fmaxf(m, v[j]); }
#pragma unroll
  for (int off = 1; off < 64; off <<= 1) m = fmaxf(m, __shfl_xor(m, off, 64));
  if ((tid & 63) == 0) redm[tid >> 6] = m;
  __syncthreads();
  m = fmaxf(fmaxf(redm[0], redm[1]), fmaxf(redm[2], redm[3]));
  float sum = 0.f;
#pragma unroll
  for (int j = 0; j < 8; ++j) { v[j] = __expf(v[j] - m); sum += v[j]; }
#pragma unroll
  for (int off = 1; off < 64; off <<= 1) sum += __shfl_xor(sum, off, 64);
  if ((tid & 63) == 0) reds[tid >> 6] = sum;
  __syncthreads();
  sum = reds[0] + reds[1] + reds[2] + reds[3];
  const float inv = 1.0f / sum;
#pragma unroll
  for (int j = 0; j < 8; ++j) pa[tid + j * 256] = v[j] * inv;
  __syncthreads();

  // attn output for this block's 64 rows
  if (tid < 64) attn[(size_t)b * NT + tc * 64 + tid] = pa[tc * 64 + tid];

  // --- partial context: sum_t pa[t] * value[t,:] over this 64-row chunk
  const float* a = &pa[tc * 64];
  const int half = tid >> 7;        // 0: even rows, 1: odd rows
  const int vi = (tid & 127) * 4;   // 128 threads cover VD=512
  const float* vp = value + ((size_t)b * NT + tc * 64 + half) * NVD + vi;
  fx4 s4 = fx4{0.f, 0.f, 0.f, 0.f};
#pragma unroll 8
  for (int t = 0; t < 64; t += 2) {
    fx4 x = *(const fx4*)(vp + (size_t)t * NVD);
    s4 += x * a[t + half];
  }
  if (half) red[tid & 127] = s4;
  __syncthreads();
  if (!half) {
    s4 += red[tid];
    *(fx4*)(partial + (size_t)blk * NVD + vi) = s4;
  }
}

// ---- kernel 4: reduce partials -> context (partials pre-normalized)
__global__ void ctx_reduce_kernel(const float* __restrict__ partial, float* __restrict__ ctx) {
  const int i = blockIdx.x * 256 + threadIdx.x;  // < NB*NVD
  const int b = i >> 9, v = i & (NVD - 1);
  float s = 0.f;
#pragma unroll
  for (int tc = 0; tc < 32; ++tc) s += partial[(size_t)(b * 32 + tc) * NVD + v];
  ctx[i] = s;
}

extern "C" void kernel_launch(void* const* d_in, const int* in_sizes, int n_in,
                              void* d_out, int out_size, void* d_ws, size_t ws_size,
                              hipStream_t stream) {
  const float* query = (const float*)d_in[0];
  const float* key   = (const float*)d_in[1];
  const float* value = (const float*)d_in[2];
  const float* Wq    = (const float*)d_in[3];
  const float* bq    = (const float*)d_in[4];
  const float* Wk    = (const float*)d_in[5];
  const float* bk    = (const float*)d_in[6];
  const float* Wo    = (const float*)d_in[7];
  // d_in[8] = bo: unused — softmax over T is invariant to a uniform shift.

  float* out  = (float*)d_out;
  float* ctx  = out;                // [B][VD]
  float* attn = out + NB * NVD;     // [B][T]

  char* ws = (char*)d_ws;
  float* qpk     = (float*)(ws);                                   // 64 KB
  short* Bpk     = (short*)(ws + 64 * 1024);                       // 256 KB
  float* score   = (float*)(ws + (64 + 256) * 1024);               // 512 KB
  float* partial = (float*)(ws + (64 + 256 + 512) * 1024);         // 4 MB

  prep_kernel<<<NB + 16, 256, 0, stream>>>(query, Wq, bq, bk, Wk, qpk, Bpk);
  score_kernel<<<(NB * NT) / 128, 512, 0, stream>>>(key, Bpk, qpk, Wo, score);
  ctx_sm_kernel<<<NB * 32, 256, 0, stream>>>(score, value, attn, partial);
  ctx_reduce_kernel<<<(NB * NVD) / 256, 256, 0, stream>>>(partial, ctx);
}